// Round 1
// baseline (42605.838 us; speedup 1.0000x reference)
//
#include <hip/hip_runtime.h>
#include <cstdint>

#define T_LEN 16384
#define X_DIM 256
#define H_DIM 1024
#define NWG   64

typedef unsigned int u32;
typedef u32   u32x4 __attribute__((ext_vector_type(4)));
typedef float f32x4 __attribute__((ext_vector_type(4)));

// ---------------------------------------------------------------------------
// Coherent (device-scope, L2-bypassing) 16B loads/stores. Per-XCD L2s are not
// cross-coherent on gfx950; sc0 sc1 makes the MALL (L3) the coherence point.
// Each consumer 16B load corresponds to exactly one producer 16B store, so
// (val,tag) pairs inside one dwordx4 cannot tear across stores.
// ---------------------------------------------------------------------------
__device__ __forceinline__ void coh_load2(const u32* p0, const u32* p1,
                                          u32x4& a, u32x4& b) {
  asm volatile(
      "global_load_dwordx4 %0, %2, off sc0 sc1\n\t"
      "global_load_dwordx4 %1, %3, off sc0 sc1\n\t"
      "s_waitcnt vmcnt(0)"
      : "=&v"(a), "=&v"(b)
      : "v"(p0), "v"(p1)
      : "memory");
}

__device__ __forceinline__ void coh_store(u32* p, u32x4 v) {
  asm volatile("global_store_dwordx4 %0, %1, off sc0 sc1"
               :: "v"(p), "v"(v) : "memory");
}

__device__ __forceinline__ float fast_tanh(float x) {
  // tanh(x) = (e^{2x}-1)/(e^{2x}+1); clamp so e never becomes inf (inf/inf=NaN).
  x = fminf(9.0f, fmaxf(-9.0f, x));
#if __has_builtin(__builtin_amdgcn_exp2f)
  const float e = __builtin_amdgcn_exp2f(x * 2.8853900817779268f); // 2*log2(e)
#else
  const float e = exp2f(x * 2.8853900817779268f);
#endif
  return (e - 1.0f) * __builtin_amdgcn_rcpf(e + 1.0f);
}

// ---------------------------------------------------------------------------
// Kernel 1: Bx_c = x @ B^T + c  written into d_out (which doubles as the bx
// buffer for the scan; each scan wave reads bx for exactly the rows it later
// overwrites, after the read -> no hazard).
// Block: 256 threads -> 64(t) x 64(h) tile, K staged 64 at a time in LDS.
// ---------------------------------------------------------------------------
__global__ __launch_bounds__(256) void gemm_bx(const float* __restrict__ x,
                                               const float* __restrict__ Bm,
                                               const float* __restrict__ c,
                                               float* __restrict__ out) {
  __shared__ float xs[64][68];  // [k][t], stride 68 keeps float4 16B-aligned
  __shared__ float bs[64][68];  // [k][h]

  const int tid = threadIdx.x;
  const int t0  = blockIdx.x * 64;
  const int h0  = blockIdx.y * 64;
  const int lr  = tid >> 4;   // 0..15 -> rows 4*lr..4*lr+3 of tile
  const int lc  = tid & 15;   // 0..15 -> cols 4*lc..4*lc+3 of tile

  float acc[4][4] = {};

  for (int kb = 0; kb < X_DIM; kb += 64) {
    const int kk  = (tid & 15) * 4;
    const int tt0 = tid >> 4;
#pragma unroll
    for (int i = 0; i < 4; ++i) {
      const int tt = tt0 + i * 16;
      const f32x4 xv = *(const f32x4*)(x  + (size_t)(t0 + tt) * X_DIM + kb + kk);
      const f32x4 bv = *(const f32x4*)(Bm + (size_t)(h0 + tt) * X_DIM + kb + kk);
#pragma unroll
      for (int q = 0; q < 4; ++q) {
        xs[kk + q][tt] = xv[q];
        bs[kk + q][tt] = bv[q];
      }
    }
    __syncthreads();

#pragma unroll 8
    for (int k = 0; k < 64; ++k) {
      const f32x4 xv = *(const f32x4*)&xs[k][lr * 4];
      const f32x4 bv = *(const f32x4*)&bs[k][lc * 4];
#pragma unroll
      for (int i = 0; i < 4; ++i)
#pragma unroll
        for (int j = 0; j < 4; ++j)
          acc[i][j] = fmaf(xv[i], bv[j], acc[i][j]);
    }
    __syncthreads();
  }

  const f32x4 cv = *(const f32x4*)(c + h0 + lc * 4);
#pragma unroll
  for (int i = 0; i < 4; ++i) {
    f32x4 o;
#pragma unroll
    for (int j = 0; j < 4; ++j) o[j] = acc[i][j] + cv[j];
    *(f32x4*)(out + (size_t)(t0 + lr * 4 + i) * H_DIM + h0 + lc * 4) = o;
  }
}

// ---------------------------------------------------------------------------
// Kernel 2: persistent scan. 64 wgs x 256 threads (4 waves). Wave v of wg w
// owns rows w*16+4v .. +3 of h; lane holds A[4 rows][16 cols] in registers.
// Cross-wg h broadcast: (val,tag) pairs via L3 with tag==step polling;
// ping-pong buffers in d_ws. One __syncthreads per step (LDS double-buffer).
// ---------------------------------------------------------------------------
__global__ __launch_bounds__(256) void rnn_scan(const float* __restrict__ A_raw,
                                                const float* __restrict__ h0,
                                                float* __restrict__ out,
                                                u32* __restrict__ pairs) {
  const int tid     = threadIdx.x;
  const int lane    = tid & 63;
  const int wv      = tid >> 6;
  const int wg      = blockIdx.x;
  const int rowbase = wg * 16 + wv * 4;

  // Load A fragment: a[r][j] = 0.1*A_raw[row][col] + 0.9*(row==col)
  float a[4][16];
#pragma unroll
  for (int r = 0; r < 4; ++r) {
    const int row = rowbase + r;
    const float* ap = A_raw + (size_t)row * H_DIM + lane * 16;
#pragma unroll
    for (int q = 0; q < 4; ++q) {
      const f32x4 v = *(const f32x4*)(ap + q * 4);
#pragma unroll
      for (int j = 0; j < 4; ++j) {
        const int col = lane * 16 + q * 4 + j;
        a[r][q * 4 + j] = 0.1f * v[j] + (col == row ? 0.9f : 0.0f);
      }
    }
  }

  // h staging in LDS, double buffered; chunk k (16 floats) at stride 20
  // (16B-aligned, conflict-free b128 reads).
  __shared__ float hs[2 * 64 * 20];
  const int chunk = tid >> 2;          // which 16-col chunk this thread polls
  const int pos   = (tid & 3) * 4;     // 4 cols within the chunk

  for (int t = 0; t < T_LEN; ++t) {
    // Prefetch bx for this wave's rows (d_out still holds Bx_c at row t).
    const f32x4 bx4 = *(const f32x4*)(out + (size_t)t * H_DIM + rowbase);

    float* lds_w = hs + (t & 1) * (64 * 20) + chunk * 20 + pos;

    if (t == 0) {
      const f32x4 h = *(const f32x4*)(h0 + tid * 4);
      lds_w[0] = h[0]; lds_w[1] = h[1]; lds_w[2] = h[2]; lds_w[3] = h[3];
    } else {
      // Poll own 4 pairs (cols 4*tid..4*tid+3) of h_t until tag == t.
      const u32* base = pairs + (size_t)(t & 1) * (H_DIM * 2) + tid * 8;
      u32x4 p0, p1;
      const u32 tag = (u32)t;
      for (;;) {
        coh_load2(base, base + 4, p0, p1);
        const bool ok = (p0.y == tag) & (p0.w == tag) &
                        (p1.y == tag) & (p1.w == tag);
        if (__all((int)ok)) break;
      }
      lds_w[0] = __uint_as_float(p0.x);
      lds_w[1] = __uint_as_float(p0.z);
      lds_w[2] = __uint_as_float(p1.x);
      lds_w[3] = __uint_as_float(p1.z);
    }
    __syncthreads();

    // acc[r] = sum over this lane's 16 cols of A[row r] * h
    const float* lds_r = hs + (t & 1) * (64 * 20) + lane * 20;
    float acc0 = 0.f, acc1 = 0.f, acc2 = 0.f, acc3 = 0.f;
#pragma unroll
    for (int j = 0; j < 16; ++j) {
      const float hv = lds_r[j];
      acc0 = fmaf(a[0][j], hv, acc0);
      acc1 = fmaf(a[1][j], hv, acc1);
      acc2 = fmaf(a[2][j], hv, acc2);
      acc3 = fmaf(a[3][j], hv, acc3);
    }
    // Full butterfly: every lane ends with all four row sums.
#pragma unroll
    for (int d = 1; d < 64; d <<= 1) {
      acc0 += __shfl_xor(acc0, d, 64);
      acc1 += __shfl_xor(acc1, d, 64);
      acc2 += __shfl_xor(acc2, d, 64);
      acc3 += __shfl_xor(acc3, d, 64);
    }

    const float v0 = fast_tanh(acc0 + bx4[0]);
    const float v1 = fast_tanh(acc1 + bx4[1]);
    const float v2 = fast_tanh(acc2 + bx4[2]);
    const float v3 = fast_tanh(acc3 + bx4[3]);

    if (lane == 0) {
      // Publish h_{t+1} slice as (val, tag=t+1) pairs into the other buffer.
      const u32 tg = (u32)(t + 1);
      u32* dst = pairs + (size_t)((t + 1) & 1) * (H_DIM * 2) + rowbase * 2;
      u32x4 s0, s1;
      s0.x = __float_as_uint(v0); s0.y = tg; s0.z = __float_as_uint(v1); s0.w = tg;
      s1.x = __float_as_uint(v2); s1.y = tg; s1.z = __float_as_uint(v3); s1.w = tg;
      coh_store(dst, s0);
      coh_store(dst + 4, s1);
    } else if (lane == 1) {
      // Output write (overwrites the bx we already consumed). Normal cached
      // store; flushed by kernel-end release.
      f32x4 o; o[0] = v0; o[1] = v1; o[2] = v2; o[3] = v3;
      *(f32x4*)(out + (size_t)t * H_DIM + rowbase) = o;
    }
    // No trailing barrier: next step writes the other LDS buffer.
  }
}

// ---------------------------------------------------------------------------
extern "C" void kernel_launch(void* const* d_in, const int* in_sizes, int n_in,
                              void* d_out, int out_size, void* d_ws, size_t ws_size,
                              hipStream_t stream) {
  const float* x    = (const float*)d_in[0];  // (T, X)
  const float* h0   = (const float*)d_in[1];  // (H,)
  const float* Araw = (const float*)d_in[2];  // (H, H)
  const float* B    = (const float*)d_in[3];  // (H, X)
  const float* c    = (const float*)d_in[4];  // (H,)
  float* out = (float*)d_out;                 // (T, H)
  u32* pairs = (u32*)d_ws;                    // 2 * H * 8 bytes = 16 KB

  dim3 g(T_LEN / 64, H_DIM / 64);
  gemm_bx<<<g, 256, 0, stream>>>(x, B, c, out);
  rnn_scan<<<NWG, 256, 0, stream>>>(Araw, h0, out, pairs);
}